// Round 5
// baseline (76.210 us; speedup 1.0000x reference)
//
#include <hip/hip_runtime.h>

// CALIBRATION ROUND: identical kernel to round 4, launched 4x per call.
// dur_us = fixed_overhead + 4*T  ->  delta vs round-4 bench = 3*T_steady.
// Distinguishes H1 (kernel ~20us) from H2 (kernel ~3us, near HBM floor),
// since the per-dispatch rocprof top-5 only shows the harness's 41us
// 268MB d_ws re-poison fill and never our kernel.
//
// dw = LR * (post^T @ pre / B - WD * W)   via bf16 MFMA (32x32x16)

using f32x16 = __attribute__((ext_vector_type(16))) float;
using short8 = __attribute__((ext_vector_type(8))) short;

constexpr int   N    = 1024;
constexpr int   K    = 128;
constexpr int   LSTR = 136;   // bf16 elems per LDS row (128 + 8 pad)
constexpr float LR   = 0.005f;
constexpr float WD   = 0.0001f;

__device__ inline unsigned short f2bf(float x) {
    union { float f; unsigned int u; } c; c.f = x;
    // round-to-nearest-even
    return (unsigned short)((c.u + 0x7FFFu + ((c.u >> 16) & 1u)) >> 16);
}

__global__ __launch_bounds__(64) void hebb_mfma(
    const float* __restrict__ pre,
    const float* __restrict__ post,
    const float* __restrict__ W,
    float* __restrict__ out)
{
    __shared__ unsigned short A_lds[32 * LSTR];  // A[m][k] = post[k][bm+m]
    __shared__ unsigned short B_lds[32 * LSTR];  // B[n][k] = pre [k][bn+n]

    const int l  = threadIdx.x;        // lane 0..63
    const int bm = blockIdx.y * 32;    // post rows of this tile
    const int bn = blockIdx.x * 32;    // pre  cols of this tile

    // staging task split: 8 m-groups x 8 k-groups (x2 passes for K=128)
    const int m4 = (l & 7) * 4;        // 4 consecutive m per thread
    const int k8 = (l >> 3) * 8;       // 8 consecutive k per thread

    #pragma unroll
    for (int p = 0; p < 2; ++p) {
        const int kb = k8 + p * 64;
        float4 av[8], bv[8];
        #pragma unroll
        for (int j = 0; j < 8; ++j) {
            av[j] = *(const float4*)(post + (size_t)(kb + j) * N + bm + m4);
            bv[j] = *(const float4*)(pre  + (size_t)(kb + j) * N + bn + m4);
        }
        #pragma unroll
        for (int i = 0; i < 4; ++i) {
            short8 pa, pb;
            #pragma unroll
            for (int j = 0; j < 8; ++j) {
                const float* fa = (const float*)&av[j];
                const float* fb = (const float*)&bv[j];
                pa[j] = (short)f2bf(fa[i]);   // A[m4+i][kb+j]
                pb[j] = (short)f2bf(fb[i]);   // B[n4+i][kb+j]
            }
            *(short8*)&A_lds[(m4 + i) * LSTR + kb] = pa;
            *(short8*)&B_lds[(m4 + i) * LSTR + kb] = pb;
        }
    }

    // W prefetch into registers: overlaps the LDS drain + MFMA loop.
    // C/D layout (m74/m101): col = lane&31, row = (reg&3)+8*(reg>>2)+4*(lane>>5)
    const int col   = l & 31;
    const int rbase = 4 * (l >> 5);
    float wv[16];
    #pragma unroll
    for (int r = 0; r < 16; ++r) {
        const int row = (r & 3) + 8 * (r >> 2) + rbase;
        wv[r] = W[(size_t)(bm + row) * N + bn + col];
    }

    __syncthreads();

    // K-loop: 8 x mfma_32x32x16. A-frag: lane l = row l&31, k = 8*(l>>5)+j.
    f32x16 acc = {};
    const int hh = 8 * (l >> 5);
    #pragma unroll
    for (int kk = 0; kk < 8; ++kk) {
        short8 a = *(const short8*)&A_lds[(l & 31) * LSTR + kk * 16 + hh];
        short8 b = *(const short8*)&B_lds[(l & 31) * LSTR + kk * 16 + hh];
        acc = __builtin_amdgcn_mfma_f32_32x32x16_bf16(a, b, acc, 0, 0, 0);
    }

    // epilogue: dw = (LR/B)*acc - (LR*WD)*W
    const float s1 = LR / 128.0f;
    const float s2 = LR * WD;
    #pragma unroll
    for (int r = 0; r < 16; ++r) {
        const int row = (r & 3) + 8 * (r >> 2) + rbase;
        out[(size_t)(bm + row) * N + bn + col] = s1 * acc[r] - s2 * wv[r];
    }
}

extern "C" void kernel_launch(void* const* d_in, const int* in_sizes, int n_in,
                              void* d_out, int out_size, void* d_ws, size_t ws_size,
                              hipStream_t stream) {
    const float* pre  = (const float*)d_in[0];  // pre_spikes  (128, 1024)
    const float* post = (const float*)d_in[1];  // post_spikes (128, 1024)
    const float* W    = (const float*)d_in[2];  // weights     (1024, 1024)
    float* out = (float*)d_out;

    dim3 grid(N / 32, N / 32);  // 32 x 32 = 1024 blocks -> 4 blocks/CU
    dim3 block(64);             // 1 wave per block

    // 4x identical idempotent launches: calibrates per-launch kernel time
    // T = (dur_us - round4_dur_us) / 3 without needing our dispatch in the
    // rocprof top-5. Same work every call; graph-capture safe.
    #pragma unroll
    for (int rep = 0; rep < 4; ++rep)
        hebb_mfma<<<grid, block, 0, stream>>>(pre, post, W, out);
}

// Round 6
// 65.493 us; speedup vs baseline: 1.1636x; 1.1636x over previous
//
#include <hip/hip_runtime.h>

// dw = LR * (post^T @ pre / B - WD * W)   via bf16 MFMA (16x16x32)
//
// Round-5 calibration: kernel T ~= 4.4us vs 2.1us HBM floor; limited by
// occupancy (1024 single-wave blocks = 1 wave/SIMD, too few outstanding
// HBM bytes per Little's law). This round: 16x16 tiles -> 4096 independent
// single-wave blocks = 4 waves/SIMD, 4x the latency hiding, no cross-wave
// sync. LDS 8.7KB/block (16 blocks/CU fits 139KB < 160KB).
//
// pre:  (K=128, N=1024) f32   post: (K=128, N=1024) f32
// W/out: (1024,1024) f32

using f32x4  = __attribute__((ext_vector_type(4))) float;
using short8 = __attribute__((ext_vector_type(8))) short;

constexpr int   N    = 1024;
constexpr int   LSTR = 136;   // bf16 elems per LDS row (128 + 8 pad)
constexpr float LR   = 0.005f;
constexpr float WD   = 0.0001f;

__device__ inline unsigned short f2bf(float x) {
    union { float f; unsigned int u; } c; c.f = x;
    return (unsigned short)((c.u + 0x7FFFu + ((c.u >> 16) & 1u)) >> 16);  // RNE
}

__global__ __launch_bounds__(64, 4) void hebb_mfma16(
    const float* __restrict__ pre,
    const float* __restrict__ post,
    const float* __restrict__ W,
    float* __restrict__ out)
{
    __shared__ unsigned short A_lds[16 * LSTR];  // A[m][k] = post[k][bm+m]
    __shared__ unsigned short B_lds[16 * LSTR];  // B[n][k] = pre [k][bn+n]

    const int l  = threadIdx.x;        // lane 0..63
    const int bm = blockIdx.y * 16;    // post rows of this tile
    const int bn = blockIdx.x * 16;    // pre  cols of this tile

    // staging split: 4 m-groups x 16 k-groups; one pass covers K=128.
    const int m4 = (l & 3) * 4;        // 4 consecutive m per lane
    const int k8 = (l >> 2) * 8;       // 8 consecutive k per lane

    // --- tile A (post), then tile B (pre): keeps live float4 count at 8 ---
    {
        float4 v[8];
        #pragma unroll
        for (int j = 0; j < 8; ++j)
            v[j] = *(const float4*)(post + (size_t)(k8 + j) * N + bm + m4);
        #pragma unroll
        for (int i = 0; i < 4; ++i) {
            short8 p;
            #pragma unroll
            for (int j = 0; j < 8; ++j) p[j] = (short)f2bf(((const float*)&v[j])[i]);
            *(short8*)&A_lds[(m4 + i) * LSTR + k8] = p;
        }
    }
    {
        float4 v[8];
        #pragma unroll
        for (int j = 0; j < 8; ++j)
            v[j] = *(const float4*)(pre + (size_t)(k8 + j) * N + bn + m4);
        #pragma unroll
        for (int i = 0; i < 4; ++i) {
            short8 p;
            #pragma unroll
            for (int j = 0; j < 8; ++j) p[j] = (short)f2bf(((const float*)&v[j])[i]);
            *(short8*)&B_lds[(m4 + i) * LSTR + k8] = p;
        }
    }

    // W prefetch (HBM stream) — issued before the barrier so it overlaps
    // the LDS drain + MFMA. C/D layout (m89): col = lane&15, row = 4*(lane>>4)+reg.
    const int col   = l & 15;
    const int rbase = 4 * (l >> 4);
    float wv[4];
    #pragma unroll
    for (int r = 0; r < 4; ++r)
        wv[r] = W[(size_t)(bm + rbase + r) * N + bn + col];

    __syncthreads();  // single-wave block: compiles to waitcnt only

    // K-loop: 4 x mfma_16x16x32. A-frag: lane l = row l&15, k = 8*(l>>4)+j.
    f32x4 acc = {};
    const int hh = 8 * (l >> 4);
    #pragma unroll
    for (int kk = 0; kk < 4; ++kk) {
        short8 a = *(const short8*)&A_lds[(l & 15) * LSTR + kk * 32 + hh];
        short8 b = *(const short8*)&B_lds[(l & 15) * LSTR + kk * 32 + hh];
        acc = __builtin_amdgcn_mfma_f32_16x16x32_bf16(a, b, acc, 0, 0, 0);
    }

    // epilogue: dw = (LR/B)*acc - (LR*WD)*W
    const float s1 = LR / 128.0f;
    const float s2 = LR * WD;
    #pragma unroll
    for (int r = 0; r < 4; ++r)
        out[(size_t)(bm + rbase + r) * N + bn + col] = s1 * acc[r] - s2 * wv[r];
}

extern "C" void kernel_launch(void* const* d_in, const int* in_sizes, int n_in,
                              void* d_out, int out_size, void* d_ws, size_t ws_size,
                              hipStream_t stream) {
    const float* pre  = (const float*)d_in[0];  // pre_spikes  (128, 1024)
    const float* post = (const float*)d_in[1];  // post_spikes (128, 1024)
    const float* W    = (const float*)d_in[2];  // weights     (1024, 1024)
    float* out = (float*)d_out;

    dim3 grid(N / 16, N / 16);  // 64 x 64 = 4096 blocks -> 16 blocks/CU
    dim3 block(64);             // 1 wave per block
    hebb_mfma16<<<grid, block, 0, stream>>>(pre, post, W, out);
}

// Round 7
// 62.975 us; speedup vs baseline: 1.2102x; 1.0400x over previous
//
#include <hip/hip_runtime.h>

// dw = LR * (post^T @ pre / B - WD * W)   via bf16 MFMA (32x32x16)
//
// Round-7: same 1024 x 1-wave blocks / 32x32 tiles as round 4 (best so
// far, T~4.4us), but the intra-wave pipeline is restructured for maximal
// memory-level parallelism: ALL global loads (16 W dwords + 32 spike
// float4) are issued up front, W FIRST. vmcnt retires in order, so the
// spike conversions implicitly wait for W -- but that latency now
// overlaps the device-wide read stream instead of sitting exposed at the
// end of the chain (round-4 flaw: W was issued after both staging
// passes, adding ~900cy naked HBM latency before the epilogue).
//
// pre:  (K=128, N=1024) f32   post: (K=128, N=1024) f32
// W/out: (1024,1024) f32

using f32x16 = __attribute__((ext_vector_type(16))) float;
using short8 = __attribute__((ext_vector_type(8))) short;

constexpr int   N    = 1024;
constexpr int   LSTR = 136;   // bf16 elems per LDS row (128 + 8 pad)
constexpr float LR   = 0.005f;
constexpr float WD   = 0.0001f;

__device__ inline unsigned short f2bf(float x) {
    union { float f; unsigned int u; } c; c.f = x;
    return (unsigned short)((c.u + 0x7FFFu + ((c.u >> 16) & 1u)) >> 16);  // RNE
}

__global__ __launch_bounds__(64, 1) void hebb_mfma(
    const float* __restrict__ pre,
    const float* __restrict__ post,
    const float* __restrict__ W,
    float* __restrict__ out)
{
    __shared__ unsigned short A_lds[32 * LSTR];  // A[m][k] = post[k][bm+m]
    __shared__ unsigned short B_lds[32 * LSTR];  // B[n][k] = pre [k][bn+n]

    const int l  = threadIdx.x;        // lane 0..63
    const int bm = blockIdx.y * 32;    // post rows of this tile
    const int bn = blockIdx.x * 32;    // pre  cols of this tile

    // C/D layout (m74/m101): col = lane&31, row = (reg&3)+8*(reg>>2)+4*(lane>>5)
    const int col   = l & 31;
    const int rbase = 4 * (l >> 5);

    // ---- 1) W loads FIRST: 16 instrs, each 2 x 128B full lines ----
    float wv[16];
    #pragma unroll
    for (int r = 0; r < 16; ++r) {
        const int row = (r & 3) + 8 * (r >> 2) + rbase;
        wv[r] = W[(size_t)(bm + row) * N + bn + col];
    }

    // ---- 2) ALL spike loads in one batch (32 x dwordx4, no reg reuse) ----
    const int m4 = (l & 7) * 4;        // 4 consecutive m per lane
    const int k8 = (l >> 3) * 8;       // 8 consecutive k per lane
    float4 av[16], bv[16];
    #pragma unroll
    for (int j = 0; j < 16; ++j) {
        const int row = k8 + (j & 7) + (j >> 3) * 64;   // two K-halves
        av[j] = *(const float4*)(post + (size_t)row * N + bm + m4);
        bv[j] = *(const float4*)(pre  + (size_t)row * N + bn + m4);
    }

    // ---- 3) convert fp32->bf16 and stage transposed [m][k] / [n][k] ----
    #pragma unroll
    for (int p = 0; p < 2; ++p) {
        const int kb = k8 + p * 64;
        #pragma unroll
        for (int i = 0; i < 4; ++i) {
            short8 pa, pb;
            #pragma unroll
            for (int j = 0; j < 8; ++j) {
                pa[j] = (short)f2bf(((const float*)&av[p * 8 + j])[i]);
                pb[j] = (short)f2bf(((const float*)&bv[p * 8 + j])[i]);
            }
            *(short8*)&A_lds[(m4 + i) * LSTR + kb] = pa;
            *(short8*)&B_lds[(m4 + i) * LSTR + kb] = pb;
        }
    }

    __syncthreads();  // 1-wave block: lgkm drain (+cheap barrier)

    // ---- 4) K-loop: 8 x mfma_32x32x16. A-frag: row l&31, k = 8*(l>>5)+j ----
    f32x16 acc = {};
    const int hh = 8 * (l >> 5);
    #pragma unroll
    for (int kk = 0; kk < 8; ++kk) {
        short8 a = *(const short8*)&A_lds[(l & 31) * LSTR + kk * 16 + hh];
        short8 b = *(const short8*)&B_lds[(l & 31) * LSTR + kk * 16 + hh];
        acc = __builtin_amdgcn_mfma_f32_32x32x16_bf16(a, b, acc, 0, 0, 0);
    }

    // ---- 5) fused epilogue: dw = (LR/B)*acc - (LR*WD)*W ----
    const float s1 = LR / 128.0f;
    const float s2 = LR * WD;
    #pragma unroll
    for (int r = 0; r < 16; ++r) {
        const int row = (r & 3) + 8 * (r >> 2) + rbase;
        out[(size_t)(bm + row) * N + bn + col] = s1 * acc[r] - s2 * wv[r];
    }
}

extern "C" void kernel_launch(void* const* d_in, const int* in_sizes, int n_in,
                              void* d_out, int out_size, void* d_ws, size_t ws_size,
                              hipStream_t stream) {
    const float* pre  = (const float*)d_in[0];  // pre_spikes  (128, 1024)
    const float* post = (const float*)d_in[1];  // post_spikes (128, 1024)
    const float* W    = (const float*)d_in[2];  // weights     (1024, 1024)
    float* out = (float*)d_out;

    dim3 grid(N / 32, N / 32);  // 32 x 32 = 1024 blocks -> 4 blocks/CU, all co-resident
    dim3 block(64);             // 1 wave per block
    hebb_mfma<<<grid, block, 0, stream>>>(pre, post, W, out);
}

// Round 10
// 62.085 us; speedup vs baseline: 1.2275x; 1.0143x over previous
//
#include <hip/hip_runtime.h>

// dw = LR * (post^T @ pre / B - WD * W)   via bf16 MFMA (32x32x16)
//
// Round-8 kernel (2nd resubmit; broker timeouts): cooperative 64x64 tiles.
// 256 blocks (exactly 1/CU) x 4 waves. Spike panels (128x64) staged
// fp32->bf16 into LDS ONCE per block and shared by all 4 waves (halves
// L2 panel traffic and f2bf VALU work vs the 1024x1-wave structure of
// rounds 4/7). Each wave computes one 32x32 quadrant with the proven
// 8 x mfma_32x32x16_bf16 chain. W loads issued first; single barrier;
// fused epilogue.
//
// pre:  (K=128, N=1024) f32   post: (K=128, N=1024) f32
// W/out: (1024,1024) f32

using f32x16 = __attribute__((ext_vector_type(16))) float;
using short8 = __attribute__((ext_vector_type(8))) short;

constexpr int   N    = 1024;
constexpr int   LSTR = 136;   // bf16 elems per LDS row (128 + 8 pad, 16B-aligned rows)
constexpr float LR   = 0.005f;
constexpr float WD   = 0.0001f;

__device__ inline unsigned short f2bf(float x) {
    union { float f; unsigned int u; } c; c.f = x;
    return (unsigned short)((c.u + 0x7FFFu + ((c.u >> 16) & 1u)) >> 16);  // RNE
}

__global__ __launch_bounds__(256, 1) void hebb_mfma64(
    const float* __restrict__ pre,
    const float* __restrict__ post,
    const float* __restrict__ W,
    float* __restrict__ out)
{
    __shared__ unsigned short A_lds[64 * LSTR];  // A[m][k] = post[k][bm+m], m=0..63
    __shared__ unsigned short B_lds[64 * LSTR];  // B[n][k] = pre [k][bn+n], n=0..63

    const int tid = threadIdx.x;       // 0..255
    const int l   = tid & 63;          // lane
    const int w   = tid >> 6;          // wave 0..3
    const int wr  = (w >> 1) * 32;     // quadrant row offset
    const int wc  = (w & 1) * 32;      // quadrant col offset
    const int bm  = blockIdx.y * 64;
    const int bn  = blockIdx.x * 64;

    // C/D layout (m74/m101): col = lane&31, row = (reg&3)+8*(reg>>2)+4*(lane>>5)
    const int col   = l & 31;
    const int rbase = 4 * (l >> 5);

    // ---- 1) W loads first (16 dwords/lane; 128B-line coalesced) ----
    float wv[16];
    #pragma unroll
    for (int r = 0; r < 16; ++r) {
        const int row = (r & 3) + 8 * (r >> 2) + rbase;
        wv[r] = W[(size_t)(bm + wr + row) * N + bn + wc + col];
    }

    // ---- 2) panel loads: 8 float4/thread/panel, fully coalesced ----
    // task map: m4 = 4*(tid&15) (consecutive lanes -> consecutive cols),
    //           k8 = 8*(tid>>4) (16 k-groups cover K=128 in one pass)
    const int m4 = (tid & 15) * 4;
    const int k8 = (tid >> 4) * 8;
    float4 av[8], bv[8];
    #pragma unroll
    for (int j = 0; j < 8; ++j) {
        av[j] = *(const float4*)(post + (size_t)(k8 + j) * N + bm + m4);
        bv[j] = *(const float4*)(pre  + (size_t)(k8 + j) * N + bn + m4);
    }

    // ---- 3) convert fp32->bf16, stage transposed [m][k] ----
    #pragma unroll
    for (int i = 0; i < 4; ++i) {
        short8 pa, pb;
        #pragma unroll
        for (int j = 0; j < 8; ++j) {
            pa[j] = (short)f2bf(((const float*)&av[j])[i]);
            pb[j] = (short)f2bf(((const float*)&bv[j])[i]);
        }
        *(short8*)&A_lds[(m4 + i) * LSTR + k8] = pa;
        *(short8*)&B_lds[(m4 + i) * LSTR + k8] = pb;
    }

    __syncthreads();

    // ---- 4) 8 x mfma_32x32x16 on this wave's quadrant ----
    // A-frag: lane row = wr + (l&31), k = 16*kk + 8*(l>>5) + j
    f32x16 acc = {};
    const int hh = 8 * (l >> 5);
    #pragma unroll
    for (int kk = 0; kk < 8; ++kk) {
        short8 a = *(const short8*)&A_lds[(wr + (l & 31)) * LSTR + kk * 16 + hh];
        short8 b = *(const short8*)&B_lds[(wc + (l & 31)) * LSTR + kk * 16 + hh];
        acc = __builtin_amdgcn_mfma_f32_32x32x16_bf16(a, b, acc, 0, 0, 0);
    }

    // ---- 5) fused epilogue: dw = (LR/B)*acc - (LR*WD)*W ----
    const float s1 = LR / 128.0f;
    const float s2 = LR * WD;
    #pragma unroll
    for (int r = 0; r < 16; ++r) {
        const int row = (r & 3) + 8 * (r >> 2) + rbase;
        out[(size_t)(bm + wr + row) * N + bn + wc + col] = s1 * acc[r] - s2 * wv[r];
    }
}

extern "C" void kernel_launch(void* const* d_in, const int* in_sizes, int n_in,
                              void* d_out, int out_size, void* d_ws, size_t ws_size,
                              hipStream_t stream) {
    const float* pre  = (const float*)d_in[0];  // pre_spikes  (128, 1024)
    const float* post = (const float*)d_in[1];  // post_spikes (128, 1024)
    const float* W    = (const float*)d_in[2];  // weights     (1024, 1024)
    float* out = (float*)d_out;

    dim3 grid(16, 16);   // 256 blocks of 64x64 tiles -> exactly 1 block/CU
    dim3 block(256);     // 4 waves
    hebb_mfma64<<<grid, block, 0, stream>>>(pre, post, W, out);
}

// Round 12
// 61.374 us; speedup vs baseline: 1.2417x; 1.0116x over previous
//
#include <hip/hip_runtime.h>
#include <hip/hip_bf16.h>

// dw = LR * (post^T @ pre / B - WD * W)   via bf16 MFMA (32x32x16)
//
// Round-11 kernel (resubmit; broker timeout): round-10 cooperative 64x64
// structure + two micro-levers:
//  (a) fp32->bf16 via __float2bfloat16 scalar casts (compiler emits
//      v_cvt_pk_bf16_f32 pairs; ~4x fewer VALU ops than the manual
//      integer RNE of rounds 2-10).
//  (b) XCD-aware bijective block swizzle: each XCD owns a 4x8 rectangle
//      of the 16x16 tile grid -> per-XCD spike footprint drops from
//      ~576KB (all of post) to ~384KB -> ~1.5MB less HBM fetch (T1).
//
// 256 blocks (1/CU) x 4 waves; panels staged once per block, shared by
// 4 waves; each wave computes one 32x32 quadrant with 8 x mfma_32x32x16;
// W loads first; single barrier; fused epilogue.
//
// pre:  (K=128, N=1024) f32   post: (K=128, N=1024) f32
// W/out: (1024,1024) f32

using f32x16 = __attribute__((ext_vector_type(16))) float;
using short8 = __attribute__((ext_vector_type(8))) short;

constexpr int   N    = 1024;
constexpr int   LSTR = 136;   // bf16 elems per LDS row (128 + 8 pad, 16B-aligned rows)
constexpr float LR   = 0.005f;
constexpr float WD   = 0.0001f;

__device__ inline unsigned short f2bf(float x) {
    __hip_bfloat16 h = __float2bfloat16(x);   // RNE; compiler packs pairs
    unsigned short u;
    __builtin_memcpy(&u, &h, 2);
    return u;
}

__global__ __launch_bounds__(256, 1) void hebb_mfma64(
    const float* __restrict__ pre,
    const float* __restrict__ post,
    const float* __restrict__ W,
    float* __restrict__ out)
{
    __shared__ unsigned short A_lds[64 * LSTR];  // A[m][k] = post[k][bm+m]
    __shared__ unsigned short B_lds[64 * LSTR];  // B[n][k] = pre [k][bn+n]

    // --- XCD rectangle swizzle (bijective on 256 blocks, 8 XCDs x 32) ---
    // xcd = id&7 owns tiles by in [4*(xcd>>1), +4), bx in [8*(xcd&1), +8)
    const int id  = blockIdx.x;
    const int xcd = id & 7;
    const int loc = id >> 3;                  // 0..31 within XCD
    const int by  = (xcd >> 1) * 4 + (loc >> 3);
    const int bx  = (xcd & 1) * 8 + (loc & 7);
    const int bm  = by * 64;
    const int bn  = bx * 64;

    const int tid = threadIdx.x;       // 0..255
    const int l   = tid & 63;          // lane
    const int w   = tid >> 6;          // wave 0..3
    const int wr  = (w >> 1) * 32;     // quadrant row offset
    const int wc  = (w & 1) * 32;      // quadrant col offset

    // C/D layout (m74/m101): col = lane&31, row = (reg&3)+8*(reg>>2)+4*(lane>>5)
    const int col   = l & 31;
    const int rbase = 4 * (l >> 5);

    // ---- 1) W loads first (16 dwords/lane; 128B-line coalesced) ----
    float wv[16];
    #pragma unroll
    for (int r = 0; r < 16; ++r) {
        const int row = (r & 3) + 8 * (r >> 2) + rbase;
        wv[r] = W[(size_t)(bm + wr + row) * N + bn + wc + col];
    }

    // ---- 2) panel loads: 8 float4/thread/panel, fully coalesced ----
    const int m4 = (tid & 15) * 4;     // 4 consecutive cols per thread
    const int k8 = (tid >> 4) * 8;     // 16 k-groups cover K=128
    float4 av[8], bv[8];
    #pragma unroll
    for (int j = 0; j < 8; ++j) {
        av[j] = *(const float4*)(post + (size_t)(k8 + j) * N + bm + m4);
        bv[j] = *(const float4*)(pre  + (size_t)(k8 + j) * N + bn + m4);
    }

    // ---- 3) convert fp32->bf16 (cvt_pk), stage transposed [m][k] ----
    #pragma unroll
    for (int i = 0; i < 4; ++i) {
        short8 pa, pb;
        #pragma unroll
        for (int j = 0; j < 8; ++j) {
            pa[j] = (short)f2bf(((const float*)&av[j])[i]);
            pb[j] = (short)f2bf(((const float*)&bv[j])[i]);
        }
        *(short8*)&A_lds[(m4 + i) * LSTR + k8] = pa;
        *(short8*)&B_lds[(m4 + i) * LSTR + k8] = pb;
    }

    __syncthreads();

    // ---- 4) 8 x mfma_32x32x16 on this wave's quadrant ----
    f32x16 acc = {};
    const int hh = 8 * (l >> 5);
    #pragma unroll
    for (int kk = 0; kk < 8; ++kk) {
        short8 a = *(const short8*)&A_lds[(wr + (l & 31)) * LSTR + kk * 16 + hh];
        short8 b = *(const short8*)&B_lds[(wc + (l & 31)) * LSTR + kk * 16 + hh];
        acc = __builtin_amdgcn_mfma_f32_32x32x16_bf16(a, b, acc, 0, 0, 0);
    }

    // ---- 5) fused epilogue: dw = (LR/B)*acc - (LR*WD)*W ----
    const float s1 = LR / 128.0f;
    const float s2 = LR * WD;
    #pragma unroll
    for (int r = 0; r < 16; ++r) {
        const int row = (r & 3) + 8 * (r >> 2) + rbase;
        out[(size_t)(bm + wr + row) * N + bn + wc + col] = s1 * acc[r] - s2 * wv[r];
    }
}

extern "C" void kernel_launch(void* const* d_in, const int* in_sizes, int n_in,
                              void* d_out, int out_size, void* d_ws, size_t ws_size,
                              hipStream_t stream) {
    const float* pre  = (const float*)d_in[0];  // pre_spikes  (128, 1024)
    const float* post = (const float*)d_in[1];  // post_spikes (128, 1024)
    const float* W    = (const float*)d_in[2];  // weights     (1024, 1024)
    float* out = (float*)d_out;

    dim3 grid(256);   // 1D; swizzled in-kernel to 16x16 tiles, 1 block/CU
    dim3 block(256);  // 4 waves
    hebb_mfma64<<<grid, block, 0, stream>>>(pre, post, W, out);
}